// Round 1
// baseline (465.968 us; speedup 1.0000x reference)
//
#include <hip/hip_runtime.h>
#include <hip/hip_bf16.h>

typedef __attribute__((ext_vector_type(8))) short short8;
typedef __attribute__((ext_vector_type(4))) short short4v;
typedef __attribute__((ext_vector_type(4))) float f32x4;

#define NR 8192
#define LOG2E 1.4426950408889634f

__device__ __forceinline__ short f2bf(float f) {
  return __builtin_bit_cast(short, __float2bfloat16(f));
}
__device__ __forceinline__ float bf2f(short s) {
  unsigned u = ((unsigned)(unsigned short)s) << 16;
  return __builtin_bit_cast(float, u);
}

// ---------------------------------------------------------------------------
// K1: HT = (x @ W)^T in bf16.  M=128 rows/block, N=128, K=256 (2 chunks of 128).
// A-frags straight from global x (fp32 -> bf16), B-frags from transposed W in LDS.
// 16x16x32 bf16 MFMA. A[m=lane&15][k=q*8+j], B[k][n=lane&15], C col=lane&15,
// row=(lane>>4)*4+reg (verified layouts, m89/m91).
// ---------------------------------------------------------------------------
__global__ __launch_bounds__(256) void k_gemm_h(const float* __restrict__ x,
                                                const float* __restrict__ W,
                                                short* __restrict__ HT) {
  __shared__ short WT[128][136];  // WT[f][k_local], pad 8 -> 2-way bank alias (free)
  const int tid = threadIdx.x;
  const int w = tid >> 6;
  const int L = tid & 63;
  const int lm = L & 15;
  const int q = L >> 4;
  const int i0 = blockIdx.x * 128;

  f32x4 acc[2][8];
#pragma unroll
  for (int mm = 0; mm < 2; ++mm)
#pragma unroll
    for (int nn = 0; nn < 8; ++nn) acc[mm][nn] = (f32x4){0.f, 0.f, 0.f, 0.f};

  for (int kc = 0; kc < 256; kc += 128) {
    if (kc) __syncthreads();
    // stage W[kc..kc+127][0..127] transposed into WT
#pragma unroll
    for (int p = 0; p < 16; ++p) {
      int idx = p * 256 + tid;       // 0..4095
      int k = idx >> 5;              // 0..127
      int f4 = (idx & 31) * 4;
      float4 v = *(const float4*)&W[(kc + k) * 128 + f4];
      WT[f4 + 0][k] = f2bf(v.x);
      WT[f4 + 1][k] = f2bf(v.y);
      WT[f4 + 2][k] = f2bf(v.z);
      WT[f4 + 3][k] = f2bf(v.w);
    }
    __syncthreads();
#pragma unroll
    for (int ks = 0; ks < 4; ++ks) {
      short8 afrag[2];
#pragma unroll
      for (int mm = 0; mm < 2; ++mm) {
        int row = i0 + 32 * w + 16 * mm + lm;
        const float* xp = &x[(size_t)row * 256 + kc + ks * 32 + q * 8];
        float4 xa = *(const float4*)xp;
        float4 xb = *(const float4*)(xp + 4);
        short8 af;
        af[0] = f2bf(xa.x); af[1] = f2bf(xa.y); af[2] = f2bf(xa.z); af[3] = f2bf(xa.w);
        af[4] = f2bf(xb.x); af[5] = f2bf(xb.y); af[6] = f2bf(xb.z); af[7] = f2bf(xb.w);
        afrag[mm] = af;
      }
#pragma unroll
      for (int nn = 0; nn < 8; ++nn) {
        short8 bf = *(const short8*)&WT[nn * 16 + lm][ks * 32 + q * 8];
        acc[0][nn] = __builtin_amdgcn_mfma_f32_16x16x32_bf16(afrag[0], bf, acc[0][nn], 0, 0, 0);
        acc[1][nn] = __builtin_amdgcn_mfma_f32_16x16x32_bf16(afrag[1], bf, acc[1][nn], 0, 0, 0);
      }
    }
  }
  // write C transposed: HT[f][i]
#pragma unroll
  for (int mm = 0; mm < 2; ++mm) {
    int ib = i0 + 32 * w + 16 * mm + 4 * q;
#pragma unroll
    for (int nn = 0; nn < 8; ++nn) {
      int f = nn * 16 + lm;
      short4v o;
      o[0] = f2bf(acc[mm][nn][0]);
      o[1] = f2bf(acc[mm][nn][1]);
      o[2] = f2bf(acc[mm][nn][2]);
      o[3] = f2bf(acc[mm][nn][3]);
      *(short4v*)&HT[(size_t)f * NR + ib] = o;
    }
  }
}

// ---------------------------------------------------------------------------
// K2: s_i = log2e * sum_f h[i][f]*a1[f],  t_i = log2e * sum_f h[i][f]*a2[f]
// (log2e folded in so the flash kernel uses native exp2)
// ---------------------------------------------------------------------------
__global__ __launch_bounds__(256) void k_st(const short* __restrict__ HT,
                                            const float* __restrict__ a,
                                            float* __restrict__ sv,
                                            float* __restrict__ tv) {
  int i = blockIdx.x * 256 + threadIdx.x;
  float s = 0.f, t = 0.f;
#pragma unroll 4
  for (int f = 0; f < 128; ++f) {
    float h = bf2f(HT[(size_t)f * NR + i]);
    s += h * a[f];
    t += h * a[128 + f];
  }
  sv[i] = s * LOG2E;
  tv[i] = t * LOG2E;
}

// ---------------------------------------------------------------------------
// K3: flash-GAT. Block = 128 i-rows, scans JR columns (j-split sp of S).
// P built directly in A-fragment register layout (no LDS round-trip):
// lane handles rows (i0+32w+lm, +16), j = j0+kk*32+q*8 .. +7.
// Ht tile (B operand, HT[f][j]) staged in padded LDS.
// Outputs unnormalized partials: part[sp][i][f] = sum p*h, lpart[sp][i] = sum p.
// ---------------------------------------------------------------------------
__global__ __launch_bounds__(256) void k_flash(const int* __restrict__ adj,
                                               const short* __restrict__ HT,
                                               const float* __restrict__ sv,
                                               const float* __restrict__ tv,
                                               float* __restrict__ part,
                                               float* __restrict__ lpart,
                                               int S, int JR) {
  __shared__ short Ht[128][136];
  const int tid = threadIdx.x;
  const int w = tid >> 6;
  const int L = tid & 63;
  const int lm = L & 15;
  const int q = L >> 4;
  const int sp = blockIdx.x >> 6;  // 64 i-tiles fixed
  const int it = blockIdx.x & 63;
  const int i0 = it * 128;

  const int row0 = i0 + 32 * w + lm;
  const int row1 = row0 + 16;
  const float s0 = sv[row0];
  const float s1 = sv[row1];

  f32x4 acc[2][8];
#pragma unroll
  for (int mm = 0; mm < 2; ++mm)
#pragma unroll
    for (int nn = 0; nn < 8; ++nn) acc[mm][nn] = (f32x4){0.f, 0.f, 0.f, 0.f};
  float l0 = 0.f, l1 = 0.f;

  const int ntiles = JR >> 7;
  for (int jt = 0; jt < ntiles; ++jt) {
    const int j0 = sp * JR + jt * 128;
    __syncthreads();  // previous tile's Ht readers done
#pragma unroll
    for (int c = 0; c < 8; ++c) {
      int idx = c * 256 + tid;
      int f = idx >> 4;
      int ch = idx & 15;
      *(uint4*)&Ht[f][ch * 8] = *(const uint4*)&HT[(size_t)f * NR + j0 + ch * 8];
    }
    __syncthreads();
#pragma unroll
    for (int kk = 0; kk < 4; ++kk) {
      const int jb = j0 + kk * 32 + q * 8;
      float4 t0 = *(const float4*)&tv[jb];
      float4 t1 = *(const float4*)&tv[jb + 4];
      const int4* ap0 = (const int4*)&adj[(size_t)row0 * NR + jb];
      const int4* ap1 = (const int4*)&adj[(size_t)row1 * NR + jb];
      int4 a00 = ap0[0], a01 = ap0[1];
      int4 a10 = ap1[0], a11 = ap1[1];
      float tvl[8] = {t0.x, t0.y, t0.z, t0.w, t1.x, t1.y, t1.z, t1.w};
      int av0[8] = {a00.x, a00.y, a00.z, a00.w, a01.x, a01.y, a01.z, a01.w};
      int av1[8] = {a10.x, a10.y, a10.z, a10.w, a11.x, a11.y, a11.z, a11.w};
      short8 p0, p1;
#pragma unroll
      for (int e = 0; e < 8; ++e) {
        // logits pre-scaled by log2e; lrelu(c*v) = c*lrelu(v) for c>0, and
        // lrelu(v) = max(v, 0.2v)
        float v0 = s0 + tvl[e];
        float e0 = fmaxf(v0, 0.2f * v0);
        float pp0 = (av0[e] > 0) ? __builtin_amdgcn_exp2f(e0) : 0.f;
        l0 += pp0;
        p0[e] = f2bf(pp0);
        float v1 = s1 + tvl[e];
        float e1 = fmaxf(v1, 0.2f * v1);
        float pp1 = (av1[e] > 0) ? __builtin_amdgcn_exp2f(e1) : 0.f;
        l1 += pp1;
        p1[e] = f2bf(pp1);
      }
#pragma unroll
      for (int nn = 0; nn < 8; ++nn) {
        short8 bf = *(const short8*)&Ht[nn * 16 + lm][kk * 32 + q * 8];
        acc[0][nn] = __builtin_amdgcn_mfma_f32_16x16x32_bf16(p0, bf, acc[0][nn], 0, 0, 0);
        acc[1][nn] = __builtin_amdgcn_mfma_f32_16x16x32_bf16(p1, bf, acc[1][nn], 0, 0, 0);
      }
    }
  }

  // epilogue: unnormalized numerator partials
  float* ps = part + (size_t)sp * (NR * 128);
#pragma unroll
  for (int mm = 0; mm < 2; ++mm) {
    int ib = i0 + 32 * w + 16 * mm + 4 * q;
#pragma unroll
    for (int nn = 0; nn < 8; ++nn) {
      int f = nn * 16 + lm;
#pragma unroll
      for (int r = 0; r < 4; ++r) ps[(size_t)(ib + r) * 128 + f] = acc[mm][nn][r];
    }
  }
  // denominator: reduce the 4 q-replicas of each row
  l0 += __shfl_xor(l0, 16);
  l0 += __shfl_xor(l0, 32);
  l1 += __shfl_xor(l1, 16);
  l1 += __shfl_xor(l1, 32);
  if (q == 0) {
    lpart[sp * NR + row0] = l0;
    lpart[sp * NR + row1] = l1;
  }
}

// ---------------------------------------------------------------------------
// K4: out[i][f] = sum_sp part / sum_sp lpart
// ---------------------------------------------------------------------------
__global__ __launch_bounds__(256) void k_reduce(const float* __restrict__ part,
                                                const float* __restrict__ lpart,
                                                float* __restrict__ out, int S) {
  int idx = blockIdx.x * 256 + threadIdx.x;  // i*128+f
  int i = idx >> 7;
  float sum = 0.f;
  for (int sp = 0; sp < S; ++sp) sum += part[(size_t)sp * (NR * 128) + idx];
  float l = 0.f;
  for (int sp = 0; sp < S; ++sp) l += lpart[sp * NR + i];
  out[idx] = (l > 0.f) ? sum / l : 0.f;
}

extern "C" void kernel_launch(void* const* d_in, const int* in_sizes, int n_in,
                              void* d_out, int out_size, void* d_ws, size_t ws_size,
                              hipStream_t stream) {
  const float* x = (const float*)d_in[0];    // 8192 x 256 fp32
  const int* adj = (const int*)d_in[1];      // 8192 x 8192 int32
  const float* W = (const float*)d_in[2];    // 256 x 128 fp32
  const float* a = (const float*)d_in[3];    // 256 x 1 fp32
  float* out = (float*)d_out;                // 8192 x 128 fp32

  char* ws = (char*)d_ws;
  short* HT = (short*)(ws + 0);              // 2 MB   bf16 h^T [128][8192]
  float* sv = (float*)(ws + 2097152);        // 32 KB
  float* tv = (float*)(ws + 2129920);        // 32 KB
  float* lpart = (float*)(ws + 2162688);     // S*32 KB
  float* part = (float*)(ws + 2424832);      // S*4 MB

  int S = 8;  // j-splits (power of 2 so 128 | 8192/S)
  while (S > 1 && (size_t)2424832 + (size_t)S * 4194304 > ws_size) S >>= 1;
  int JR = NR / S;

  hipLaunchKernelGGL(k_gemm_h, dim3(64), dim3(256), 0, stream, x, W, HT);
  hipLaunchKernelGGL(k_st, dim3(32), dim3(256), 0, stream, HT, a, sv, tv);
  hipLaunchKernelGGL(k_flash, dim3(64 * S), dim3(256), 0, stream, adj, HT, sv, tv,
                     part, lpart, S, JR);
  hipLaunchKernelGGL(k_reduce, dim3((NR * 128) / 256), dim3(256), 0, stream, part,
                     lpart, out, S);
}

// Round 2
// 450.266 us; speedup vs baseline: 1.0349x; 1.0349x over previous
//
#include <hip/hip_runtime.h>
#include <hip/hip_bf16.h>

typedef __attribute__((ext_vector_type(8))) short short8;
typedef __attribute__((ext_vector_type(4))) short short4v;
typedef __attribute__((ext_vector_type(4))) float f32x4;

#define NR 8192
#define LOG2E 1.4426950408889634f

__device__ __forceinline__ short f2bf(float f) {
  return __builtin_bit_cast(short, __float2bfloat16(f));
}

// ---------------------------------------------------------------------------
// K1: HT = (x @ W)^T in bf16, fused s,t epilogue.
// 128 blocks x 64 rows. 16x16x32 bf16 MFMA; A[m=lane&15][k=q*8+j],
// B[k][n=lane&15], C col=lane&15, row=q*4+reg (verified m89/m91).
// s_i = log2e * h[i,:]@a1, t_i = log2e * h[i,:]@a2 computed from the fp32
// accumulators via shfl_xor reduction over the 16 lm lanes.
// ---------------------------------------------------------------------------
__global__ __launch_bounds__(256) void k_gemm_h(const float* __restrict__ x,
                                                const float* __restrict__ W,
                                                const float* __restrict__ a,
                                                short* __restrict__ HT,
                                                float* __restrict__ sv,
                                                float* __restrict__ tv) {
  __shared__ short WT[128][136];  // pad 8 shorts -> 2-way alias (free, m136)
  const int tid = threadIdx.x;
  const int w = tid >> 6;
  const int L = tid & 63;
  const int lm = L & 15;
  const int q = L >> 4;
  const int i0 = blockIdx.x * 64;

  f32x4 acc[8];
#pragma unroll
  for (int nn = 0; nn < 8; ++nn) acc[nn] = (f32x4){0.f, 0.f, 0.f, 0.f};

  for (int kc = 0; kc < 256; kc += 128) {
    if (kc) __syncthreads();
#pragma unroll
    for (int p = 0; p < 16; ++p) {
      int idx = p * 256 + tid;  // 0..4095
      int k = idx >> 5;         // 0..127
      int f4 = (idx & 31) * 4;
      float4 v = *(const float4*)&W[(kc + k) * 128 + f4];
      WT[f4 + 0][k] = f2bf(v.x);
      WT[f4 + 1][k] = f2bf(v.y);
      WT[f4 + 2][k] = f2bf(v.z);
      WT[f4 + 3][k] = f2bf(v.w);
    }
    __syncthreads();
#pragma unroll
    for (int ks = 0; ks < 4; ++ks) {
      int row = i0 + 16 * w + lm;
      const float* xp = &x[(size_t)row * 256 + kc + ks * 32 + q * 8];
      float4 xa = *(const float4*)xp;
      float4 xb = *(const float4*)(xp + 4);
      short8 af;
      af[0] = f2bf(xa.x); af[1] = f2bf(xa.y); af[2] = f2bf(xa.z); af[3] = f2bf(xa.w);
      af[4] = f2bf(xb.x); af[5] = f2bf(xb.y); af[6] = f2bf(xb.z); af[7] = f2bf(xb.w);
#pragma unroll
      for (int nn = 0; nn < 8; ++nn) {
        short8 bf = *(const short8*)&WT[nn * 16 + lm][ks * 32 + q * 8];
        acc[nn] = __builtin_amdgcn_mfma_f32_16x16x32_bf16(af, bf, acc[nn], 0, 0, 0);
      }
    }
  }

  // epilogue: write HT[f][i] bf16 and reduce s,t
  const int ib = i0 + 16 * w + 4 * q;
  float a1v[8], a2v[8];
#pragma unroll
  for (int nn = 0; nn < 8; ++nn) {
    a1v[nn] = a[nn * 16 + lm];
    a2v[nn] = a[128 + nn * 16 + lm];
  }
  float sr[4] = {0.f, 0.f, 0.f, 0.f};
  float tr[4] = {0.f, 0.f, 0.f, 0.f};
#pragma unroll
  for (int nn = 0; nn < 8; ++nn) {
    int f = nn * 16 + lm;
    short4v o;
    o[0] = f2bf(acc[nn][0]);
    o[1] = f2bf(acc[nn][1]);
    o[2] = f2bf(acc[nn][2]);
    o[3] = f2bf(acc[nn][3]);
    *(short4v*)&HT[(size_t)f * NR + ib] = o;
#pragma unroll
    for (int r = 0; r < 4; ++r) {
      sr[r] += acc[nn][r] * a1v[nn];
      tr[r] += acc[nn][r] * a2v[nn];
    }
  }
#pragma unroll
  for (int d = 1; d < 16; d <<= 1) {
#pragma unroll
    for (int r = 0; r < 4; ++r) {
      sr[r] += __shfl_xor(sr[r], d);
      tr[r] += __shfl_xor(tr[r], d);
    }
  }
  if (lm == 0) {
#pragma unroll
    for (int r = 0; r < 4; ++r) {
      sv[ib + r] = sr[r] * LOG2E;
      tv[ib + r] = tr[r] * LOG2E;
    }
  }
}

// ---------------------------------------------------------------------------
// K3: flash-GAT, no LDS, no barriers. Block = 128 i-rows, 4 waves, each wave
// 32 rows (2x16). B-frags loaded straight from global HT (L2-resident, 2 MB).
// P built in A-fragment register layout. Pure streaming loop -> compiler
// software-pipelines adj (HBM) + HT (L2) loads across iterations.
// ---------------------------------------------------------------------------
__global__ __launch_bounds__(256, 3) void k_flash(const int* __restrict__ adj,
                                                  const short* __restrict__ HT,
                                                  const float* __restrict__ sv,
                                                  const float* __restrict__ tv,
                                                  float* __restrict__ part,
                                                  float* __restrict__ lpart,
                                                  int S) {
  const int tid = threadIdx.x;
  const int w = tid >> 6;
  const int L = tid & 63;
  const int lm = L & 15;
  const int q = L >> 4;
  const int sp = blockIdx.x >> 6;  // 64 i-tiles fixed
  const int it = blockIdx.x & 63;
  const int i0 = it * 128;

  const int row0 = i0 + 32 * w + lm;
  const int row1 = row0 + 16;
  const float s0 = sv[row0];
  const float s1 = sv[row1];
  const size_t ar0 = (size_t)row0 * NR;
  const size_t ar1 = (size_t)row1 * NR;

  f32x4 acc[2][8];
#pragma unroll
  for (int mm = 0; mm < 2; ++mm)
#pragma unroll
    for (int nn = 0; nn < 8; ++nn) acc[mm][nn] = (f32x4){0.f, 0.f, 0.f, 0.f};
  float l0 = 0.f, l1 = 0.f;

  const int JR = NR / S;
  const int j0 = sp * JR;
  const int niter = JR >> 5;

#pragma unroll 2
  for (int jk = 0; jk < niter; ++jk) {
    const int jb = j0 + (jk << 5) + q * 8;
    float4 t0 = *(const float4*)&tv[jb];
    float4 t1 = *(const float4*)&tv[jb + 4];
    int4 a00 = *(const int4*)&adj[ar0 + jb];
    int4 a01 = *(const int4*)&adj[ar0 + jb + 4];
    int4 a10 = *(const int4*)&adj[ar1 + jb];
    int4 a11 = *(const int4*)&adj[ar1 + jb + 4];
    short8 bf[8];
#pragma unroll
    for (int nn = 0; nn < 8; ++nn)
      bf[nn] = *(const short8*)&HT[(size_t)(nn * 16 + lm) * NR + jb];

    float tvl[8] = {t0.x, t0.y, t0.z, t0.w, t1.x, t1.y, t1.z, t1.w};
    int av0[8] = {a00.x, a00.y, a00.z, a00.w, a01.x, a01.y, a01.z, a01.w};
    int av1[8] = {a10.x, a10.y, a10.z, a10.w, a11.x, a11.y, a11.z, a11.w};
    short8 p0, p1;
#pragma unroll
    for (int e = 0; e < 8; ++e) {
      // logits pre-scaled by log2e; lrelu(v) = max(v, 0.2v)
      float v0 = s0 + tvl[e];
      float e0 = fmaxf(v0, 0.2f * v0);
      float pp0 = (av0[e] > 0) ? __builtin_amdgcn_exp2f(e0) : 0.f;
      l0 += pp0;
      p0[e] = f2bf(pp0);
      float v1 = s1 + tvl[e];
      float e1 = fmaxf(v1, 0.2f * v1);
      float pp1 = (av1[e] > 0) ? __builtin_amdgcn_exp2f(e1) : 0.f;
      l1 += pp1;
      p1[e] = f2bf(pp1);
    }
#pragma unroll
    for (int nn = 0; nn < 8; ++nn) {
      acc[0][nn] = __builtin_amdgcn_mfma_f32_16x16x32_bf16(p0, bf[nn], acc[0][nn], 0, 0, 0);
      acc[1][nn] = __builtin_amdgcn_mfma_f32_16x16x32_bf16(p1, bf[nn], acc[1][nn], 0, 0, 0);
    }
  }

  // unnormalized numerator partials
  float* ps = part + (size_t)sp * (NR * 128);
#pragma unroll
  for (int mm = 0; mm < 2; ++mm) {
    int ib = i0 + 32 * w + 16 * mm + 4 * q;
#pragma unroll
    for (int nn = 0; nn < 8; ++nn) {
      int f = nn * 16 + lm;
#pragma unroll
      for (int r = 0; r < 4; ++r) ps[(size_t)(ib + r) * 128 + f] = acc[mm][nn][r];
    }
  }
  // denominator: reduce the 4 q-replicas of each row
  l0 += __shfl_xor(l0, 16);
  l0 += __shfl_xor(l0, 32);
  l1 += __shfl_xor(l1, 16);
  l1 += __shfl_xor(l1, 32);
  if (q == 0) {
    lpart[sp * NR + row0] = l0;
    lpart[sp * NR + row1] = l1;
  }
}

// ---------------------------------------------------------------------------
// K4: out[i][f] = sum_sp part / sum_sp lpart   (float4 vectorized)
// ---------------------------------------------------------------------------
__global__ __launch_bounds__(256) void k_reduce(const float* __restrict__ part,
                                                const float* __restrict__ lpart,
                                                float* __restrict__ out, int S) {
  int idx4 = blockIdx.x * 256 + threadIdx.x;
  int idx = idx4 * 4;  // i*128+f
  int i = idx >> 7;
  float4 sum = {0.f, 0.f, 0.f, 0.f};
  for (int sp = 0; sp < S; ++sp) {
    float4 v = *(const float4*)&part[(size_t)sp * (NR * 128) + idx];
    sum.x += v.x; sum.y += v.y; sum.z += v.z; sum.w += v.w;
  }
  float l = 0.f;
  for (int sp = 0; sp < S; ++sp) l += lpart[sp * NR + i];
  float inv = (l > 0.f) ? 1.f / l : 0.f;
  float4 o = {sum.x * inv, sum.y * inv, sum.z * inv, sum.w * inv};
  *(float4*)&out[idx] = o;
}

extern "C" void kernel_launch(void* const* d_in, const int* in_sizes, int n_in,
                              void* d_out, int out_size, void* d_ws, size_t ws_size,
                              hipStream_t stream) {
  const float* x = (const float*)d_in[0];    // 8192 x 256 fp32
  const int* adj = (const int*)d_in[1];      // 8192 x 8192 int32
  const float* W = (const float*)d_in[2];    // 256 x 128 fp32
  const float* a = (const float*)d_in[3];    // 256 x 1 fp32
  float* out = (float*)d_out;                // 8192 x 128 fp32

  char* ws = (char*)d_ws;
  short* HT = (short*)(ws + 0);              // 2 MB  bf16 h^T [128][8192]
  float* sv = (float*)(ws + 2097152);        // 32 KB
  float* tv = (float*)(ws + 2129920);        // 32 KB
  float* lpart = (float*)(ws + 2162688);     // <= 16*32 KB = 512 KB
  float* part = (float*)(ws + 3145728);      // S * 4 MB

  int S = 16;  // j-splits: 1024 blocks -> 4 blocks/CU
  while (S > 1 && (size_t)3145728 + (size_t)S * 4194304 > ws_size) S >>= 1;

  hipLaunchKernelGGL(k_gemm_h, dim3(128), dim3(256), 0, stream, x, W, a, HT, sv, tv);
  hipLaunchKernelGGL(k_flash, dim3(64 * S), dim3(256), 0, stream, adj, HT, sv, tv,
                     part, lpart, S);
  hipLaunchKernelGGL(k_reduce, dim3((NR * 128) / 1024), dim3(256), 0, stream, part,
                     lpart, out, S);
}